// Round 1
// baseline (270.606 us; speedup 1.0000x reference)
//
#include <hip/hip_runtime.h>
#include <hip/hip_bf16.h>

// Problem constants
#define D       512       // embedding dim (= C)
#define K       2048      // codebook size
#define BATCH   16
#define HW      1024      // 32*32
#define N_TOK   16384     // BATCH*HW
#define NUMEL   8388608   // 16*512*32*32

typedef __attribute__((ext_vector_type(8))) short  short8;   // 8 bf16 = 4 VGPRs
typedef __attribute__((ext_vector_type(4))) float  floatx4;

// ---- ws layout (bytes) ----
// zb   : bf16 [16384][512]   @ 0          (16,777,216)
// eb   : bf16 [2048][512]    @ 16777216   ( 2,097,152)
// esq  : f32  [2048]         @ 18874368   (     8,192)
// minb : u64  [16384]        @ 18882560   (   131,072)
// loss : f32  [1]            @ 19013632
#define WS_ZB   0
#define WS_EB   16777216
#define WS_ESQ  18874368
#define WS_MINB 18882560
#define WS_LOSS 19013632

// monotone fp32 -> sortable u32
__device__ __forceinline__ unsigned int fkey(float f) {
    unsigned int b = __float_as_uint(f);
    return b ^ ((unsigned int)((int)b >> 31) | 0x80000000u);
}

// ---------------- Kernel Z: NCHW fp32 -> [N_TOK][D] bf16 (transpose+cast) ----------------
__global__ void kz(const float* __restrict__ z, __hip_bfloat16* __restrict__ zb) {
    __shared__ float t[64][65];
    int blk = blockIdx.x;            // b(16) * 128 + dt(8) * 16 + nt(16)
    int b  = blk >> 7;
    int dt = (blk >> 4) & 7;
    int nt = blk & 15;
    int d0 = dt * 64, n0 = nt * 64;
    const float* zp = z + (size_t)b * D * HW;
#pragma unroll
    for (int i = 0; i < 16; ++i) {
        int e = threadIdx.x + 256 * i;
        int r = e >> 6, c = e & 63;
        t[r][c] = zp[(size_t)(d0 + r) * HW + n0 + c];   // coalesced along hw
    }
    __syncthreads();
    __hip_bfloat16* op = zb + ((size_t)(b * HW + n0)) * D + d0;
#pragma unroll
    for (int i = 0; i < 16; ++i) {
        int e = threadIdx.x + 256 * i;
        int rn = e >> 6, cd = e & 63;
        op[(size_t)rn * D + cd] = __float2bfloat16(t[cd][rn]);  // coalesced along d
    }
}

// ---------------- Kernel E: emb -> eb bf16 + e_sq ----------------
__global__ void ke(const float* __restrict__ emb, __hip_bfloat16* __restrict__ eb,
                   float* __restrict__ esq) {
    int k = blockIdx.x;
    const float* ep = emb + (size_t)k * D;
    float s = 0.f;
    for (int d = threadIdx.x; d < D; d += 256) {
        float v = ep[d];
        s += v * v;
        eb[(size_t)k * D + d] = __float2bfloat16(v);
    }
#pragma unroll
    for (int o = 32; o; o >>= 1) s += __shfl_down(s, o);
    __shared__ float ls[4];
    if ((threadIdx.x & 63) == 0) ls[threadIdx.x >> 6] = s;
    __syncthreads();
    if (threadIdx.x == 0) esq[k] = ls[0] + ls[1] + ls[2] + ls[3];
}

// ---------------- Kernel G: bf16 MFMA GEMM + fused argmin ----------------
// grid: (N_TOK/128) * (K/128) = 128*16 = 2048 blocks, 256 threads (4 waves, 2x2)
__global__ __launch_bounds__(256) void kg(const __hip_bfloat16* __restrict__ zb,
                                          const __hip_bfloat16* __restrict__ eb,
                                          const float* __restrict__ esq,
                                          unsigned long long* __restrict__ minb) {
    // +8 bf16 pad -> row stride 144 B (34? no: 144B = 36 dwords); b128 frag reads land 2-way
    __shared__ __hip_bfloat16 As[128][72];
    __shared__ __hip_bfloat16 Bs[128][72];

    int mtile = blockIdx.x >> 4;     // consecutive blocks share mtile -> A strip L2 reuse
    int ktile = blockIdx.x & 15;
    int tid  = threadIdx.x;
    int wv   = tid >> 6;
    int lane = tid & 63;
    int wm = wv >> 1, wn = wv & 1;   // 2x2 wave grid, each wave 64x64
    int lrow  = lane & 15;
    int lquad = lane >> 4;

    floatx4 acc[4][4];
#pragma unroll
    for (int i = 0; i < 4; ++i)
#pragma unroll
        for (int j = 0; j < 4; ++j) acc[i][j] = (floatx4){0.f, 0.f, 0.f, 0.f};

    const uint4* Ag = (const uint4*)(zb + (size_t)mtile * 128 * D);  // [128][64] uint4
    const uint4* Bg = (const uint4*)(eb + (size_t)ktile * 128 * D);

    for (int d0 = 0; d0 < D; d0 += 64) {
        int c0 = d0 >> 3;   // uint4 col offset
#pragma unroll
        for (int i = 0; i < 4; ++i) {
            int e = tid + 256 * i;          // 0..1023 = 128 rows * 8 uint4
            int r = e >> 3, c8 = e & 7;
            uint4 va = Ag[(size_t)r * 64 + c0 + c8];
            uint4 vb = Bg[(size_t)r * 64 + c0 + c8];
            *(uint4*)&As[r][c8 * 8] = va;
            *(uint4*)&Bs[r][c8 * 8] = vb;
        }
        __syncthreads();
#pragma unroll
        for (int ks = 0; ks < 2; ++ks) {
            short8 af[4], bfr[4];
#pragma unroll
            for (int i = 0; i < 4; ++i) {
                af[i]  = *(const short8*)&As[wm * 64 + i * 16 + lrow][ks * 32 + lquad * 8];
                bfr[i] = *(const short8*)&Bs[wn * 64 + i * 16 + lrow][ks * 32 + lquad * 8];
            }
#pragma unroll
            for (int i = 0; i < 4; ++i)
#pragma unroll
                for (int j = 0; j < 4; ++j)
                    acc[i][j] = __builtin_amdgcn_mfma_f32_16x16x32_bf16(af[i], bfr[j], acc[i][j], 0, 0, 0);
        }
        __syncthreads();
    }

    // epilogue: dist = esq[k] - 2*dot; per-row argmin -> packed u64 atomicMin
    float es[4];
#pragma unroll
    for (int j = 0; j < 4; ++j) es[j] = esq[ktile * 128 + wn * 64 + j * 16 + lrow];

#pragma unroll
    for (int i = 0; i < 4; ++i) {
#pragma unroll
        for (int r = 0; r < 4; ++r) {
            int m_g = mtile * 128 + wm * 64 + i * 16 + lquad * 4 + r;  // C/D: row=quad*4+reg
            unsigned long long best = 0xFFFFFFFFFFFFFFFFULL;
#pragma unroll
            for (int j = 0; j < 4; ++j) {
                float dist = es[j] - 2.0f * acc[i][j][r];
                int kg_idx = ktile * 128 + wn * 64 + j * 16 + lrow;     // C/D: col=lane&15
                unsigned long long p = ((unsigned long long)fkey(dist) << 32) | (unsigned int)kg_idx;
                best = p < best ? p : best;
            }
#pragma unroll
            for (int o = 1; o < 16; o <<= 1) {
                unsigned long long other = __shfl_xor(best, o);
                best = other < best ? other : best;
            }
            if (lrow == 0) atomicMin(&minb[m_g], best);
        }
    }
}

// ---------------- Kernel O: gather + NCHW write + loss partial ----------------
__global__ void ko(const float* __restrict__ z, const float* __restrict__ emb,
                   const unsigned long long* __restrict__ minb,
                   float* __restrict__ out, float* __restrict__ loss) {
    size_t o = ((size_t)blockIdx.x * 256 + threadIdx.x) * 4;  // 4 consecutive w per thread
    int w = (int)(o & 31);
    int h = (int)((o >> 5) & 31);
    int b = (int)(o >> 19);
    int c = (int)((o >> 10) & 511);
    int nb = b * 1024 + h * 32 + w;
    float4 zv = *(const float4*)(z + o);
    float q0 = emb[(size_t)(unsigned int)(minb[nb + 0] & 0xFFFFFFFFull) * D + c];
    float q1 = emb[(size_t)(unsigned int)(minb[nb + 1] & 0xFFFFFFFFull) * D + c];
    float q2 = emb[(size_t)(unsigned int)(minb[nb + 2] & 0xFFFFFFFFull) * D + c];
    float q3 = emb[(size_t)(unsigned int)(minb[nb + 3] & 0xFFFFFFFFull) * D + c];
    *(float4*)(out + o) = make_float4(q0, q1, q2, q3);
    float d0 = q0 - zv.x, d1 = q1 - zv.y, d2 = q2 - zv.z, d3 = q3 - zv.w;
    float s = d0 * d0 + d1 * d1 + d2 * d2 + d3 * d3;
#pragma unroll
    for (int off = 32; off; off >>= 1) s += __shfl_down(s, off);
    __shared__ float ls[4];
    if ((threadIdx.x & 63) == 0) ls[threadIdx.x >> 6] = s;
    __syncthreads();
    if (threadIdx.x == 0) atomicAdd(loss, ls[0] + ls[1] + ls[2] + ls[3]);
}

// ---------------- Kernel F: finalize loss ----------------
__global__ void kf(const float* __restrict__ loss, float* __restrict__ out_loss) {
    *out_loss = 1.25f * (*loss) / 8388608.0f;   // q_latent + 0.25*e_latent, both = mean((q-z)^2)
}

extern "C" void kernel_launch(void* const* d_in, const int* in_sizes, int n_in,
                              void* d_out, int out_size, void* d_ws, size_t ws_size,
                              hipStream_t stream) {
    const float* z   = (const float*)d_in[0];   // [16,512,32,32]
    const float* emb = (const float*)d_in[1];   // [2048,512]
    char* ws = (char*)d_ws;
    __hip_bfloat16* zb  = (__hip_bfloat16*)(ws + WS_ZB);
    __hip_bfloat16* eb  = (__hip_bfloat16*)(ws + WS_EB);
    float*          esq = (float*)(ws + WS_ESQ);
    unsigned long long* minb = (unsigned long long*)(ws + WS_MINB);
    float*          loss = (float*)(ws + WS_LOSS);
    float* out = (float*)d_out;

    hipMemsetAsync(minb, 0xFF, N_TOK * 8, stream);  // u64 max
    hipMemsetAsync(loss, 0, 4, stream);
    kz<<<2048, 256, 0, stream>>>(z, zb);
    ke<<<K,    256, 0, stream>>>(emb, eb, esq);
    kg<<<2048, 256, 0, stream>>>(zb, eb, esq, minb);
    ko<<<NUMEL / 1024, 256, 0, stream>>>(z, emb, minb, out, loss);
    kf<<<1, 1, 0, stream>>>(loss, out + NUMEL);
}

// Round 2
// 195.113 us; speedup vs baseline: 1.3869x; 1.3869x over previous
//
#include <hip/hip_runtime.h>
#include <hip/hip_bf16.h>

// Problem constants
#define D       512       // embedding dim (= C)
#define K       2048      // codebook size
#define HW      1024      // 32*32
#define N_TOK   16384     // 16*HW
#define NUMEL   8388608   // 16*512*32*32

typedef __attribute__((ext_vector_type(8))) short  short8;   // 8 bf16 = 4 VGPRs
typedef __attribute__((ext_vector_type(4))) float  floatx4;

// async global->LDS DMA, 16 B per lane; LDS dest is wave-uniform base + lane*16
#define GLD_LDS16(gptr, lptr) \
    __builtin_amdgcn_global_load_lds((const __attribute__((address_space(1))) void*)(gptr), \
                                     (__attribute__((address_space(3))) void*)(lptr), 16, 0, 0)

// ---- ws layout (bytes) ----
#define WS_ZB   0           // bf16 [16384][512]
#define WS_EB   16777216    // bf16 [2048][512]
#define WS_ESQ  18874368    // f32  [2048]
#define WS_MINB 18882560    // u64  [16384]
#define WS_LOSS 19013632    // f32  [1]

// monotone fp32 -> sortable u32
__device__ __forceinline__ unsigned int fkey(float f) {
    unsigned int b = __float_as_uint(f);
    return b ^ ((unsigned int)((int)b >> 31) | 0x80000000u);
}

// ---------------- Kernel Z: NCHW fp32 -> [N_TOK][D] bf16 (transpose+cast) ----------------
__global__ __launch_bounds__(256) void kz(const float* __restrict__ z,
                                          __hip_bfloat16* __restrict__ zb) {
    __shared__ float t[64][65];
    int blk = blockIdx.x;            // b(16) * 128 + dt(8) * 16 + nt(16)
    int b  = blk >> 7;
    int dt = (blk >> 4) & 7;
    int nt = blk & 15;
    int d0 = dt * 64, n0 = nt * 64;
    const float* zp = z + ((size_t)b * D + d0) * HW + n0;
#pragma unroll
    for (int i = 0; i < 4; ++i) {
        int e = threadIdx.x + 256 * i;     // r(64) x c4(16)
        int r = e >> 4, c4 = e & 15;
        float4 v = *(const float4*)(zp + (size_t)r * HW + c4 * 4);
        t[r][c4 * 4 + 0] = v.x; t[r][c4 * 4 + 1] = v.y;
        t[r][c4 * 4 + 2] = v.z; t[r][c4 * 4 + 3] = v.w;
    }
    __syncthreads();
    __hip_bfloat16* op = zb + ((size_t)(b * HW + n0)) * D + d0;
#pragma unroll
    for (int i = 0; i < 4; ++i) {
        int e = threadIdx.x + 256 * i;     // rn(64) x cd4(16)
        int rn = e >> 4, cd4 = e & 15;
        __hip_bfloat16 q0 = __float2bfloat16(t[cd4 * 4 + 0][rn]);
        __hip_bfloat16 q1 = __float2bfloat16(t[cd4 * 4 + 1][rn]);
        __hip_bfloat16 q2 = __float2bfloat16(t[cd4 * 4 + 2][rn]);
        __hip_bfloat16 q3 = __float2bfloat16(t[cd4 * 4 + 3][rn]);
        ushort4 u;
        u.x = *(unsigned short*)&q0; u.y = *(unsigned short*)&q1;
        u.z = *(unsigned short*)&q2; u.w = *(unsigned short*)&q3;
        *(ushort4*)(op + (size_t)rn * D + cd4 * 4) = u;
    }
}

// ---------------- Kernel E: emb -> eb bf16 + e_sq ----------------
__global__ void ke(const float* __restrict__ emb, __hip_bfloat16* __restrict__ eb,
                   float* __restrict__ esq) {
    int k = blockIdx.x;
    const float* ep = emb + (size_t)k * D;
    float s = 0.f;
    for (int d = threadIdx.x; d < D; d += 256) {
        float v = ep[d];
        s += v * v;
        eb[(size_t)k * D + d] = __float2bfloat16(v);
    }
#pragma unroll
    for (int o = 32; o; o >>= 1) s += __shfl_down(s, o);
    __shared__ float ls[4];
    if ((threadIdx.x & 63) == 0) ls[threadIdx.x >> 6] = s;
    __syncthreads();
    if (threadIdx.x == 0) esq[k] = ls[0] + ls[1] + ls[2] + ls[3];
}

// ---------------- Kernel G: bf16 MFMA GEMM + fused argmin ----------------
// grid: (N_TOK/128) * (K/128) = 128*16 = 2048 blocks, 256 threads (4 waves, 2x2)
// Staging via global_load_lds width=16 (m97 structure): unpadded [128][64] LDS tiles.
__global__ __launch_bounds__(256) void kg(const __hip_bfloat16* __restrict__ zb,
                                          const __hip_bfloat16* __restrict__ eb,
                                          const float* __restrict__ esq,
                                          unsigned long long* __restrict__ minb) {
    __shared__ __hip_bfloat16 As[128][64];   // unpadded: required by global_load_lds
    __shared__ __hip_bfloat16 Bs[128][64];

    int mtile = blockIdx.x >> 4;     // consecutive blocks share mtile -> A strip L2 reuse
    int ktile = blockIdx.x & 15;
    int tid  = threadIdx.x;
    int wv   = tid >> 6;
    int lane = tid & 63;
    int wm = wv >> 1, wn = wv & 1;   // 2x2 wave grid, each wave 64x64
    int lrow  = lane & 15;
    int lquad = lane >> 4;
    int rl = lane >> 3, c8 = lane & 7;   // staging: 8 rows x 8 uint4 per wave-call

    floatx4 acc[4][4];
#pragma unroll
    for (int i = 0; i < 4; ++i)
#pragma unroll
        for (int j = 0; j < 4; ++j) acc[i][j] = (floatx4){0.f, 0.f, 0.f, 0.f};

    const uint4* Ag = (const uint4*)(zb + (size_t)mtile * 128 * D);  // [128][64] uint4
    const uint4* Bg = (const uint4*)(eb + (size_t)ktile * 128 * D);

    for (int d0 = 0; d0 < D; d0 += 64) {
        int c0 = d0 >> 3;   // uint4 col offset
#pragma unroll
        for (int ch = 0; ch < 4; ++ch) {
            int rbase = wv * 32 + ch * 8;    // wave-uniform
            GLD_LDS16(Ag + (size_t)(rbase + rl) * 64 + c0 + c8, &As[rbase][0]);
            GLD_LDS16(Bg + (size_t)(rbase + rl) * 64 + c0 + c8, &Bs[rbase][0]);
        }
        __syncthreads();
#pragma unroll
        for (int ks = 0; ks < 2; ++ks) {
            short8 af[4], bfr[4];
#pragma unroll
            for (int i = 0; i < 4; ++i) {
                af[i]  = *(const short8*)&As[wm * 64 + i * 16 + lrow][ks * 32 + lquad * 8];
                bfr[i] = *(const short8*)&Bs[wn * 64 + i * 16 + lrow][ks * 32 + lquad * 8];
            }
#pragma unroll
            for (int i = 0; i < 4; ++i)
#pragma unroll
                for (int j = 0; j < 4; ++j)
                    acc[i][j] = __builtin_amdgcn_mfma_f32_16x16x32_bf16(af[i], bfr[j], acc[i][j], 0, 0, 0);
        }
        __syncthreads();
    }

    // epilogue: dist = esq[k] - 2*dot; per-row argmin -> packed u64 atomicMin
    float es[4];
#pragma unroll
    for (int j = 0; j < 4; ++j) es[j] = esq[ktile * 128 + wn * 64 + j * 16 + lrow];

#pragma unroll
    for (int i = 0; i < 4; ++i) {
#pragma unroll
        for (int r = 0; r < 4; ++r) {
            int m_g = mtile * 128 + wm * 64 + i * 16 + lquad * 4 + r;  // C/D: row=quad*4+reg
            unsigned long long best = 0xFFFFFFFFFFFFFFFFULL;
#pragma unroll
            for (int j = 0; j < 4; ++j) {
                float dist = es[j] - 2.0f * acc[i][j][r];
                int kg_idx = ktile * 128 + wn * 64 + j * 16 + lrow;     // C/D: col=lane&15
                unsigned long long p = ((unsigned long long)fkey(dist) << 32) | (unsigned int)kg_idx;
                best = p < best ? p : best;
            }
#pragma unroll
            for (int o = 1; o < 16; o <<= 1) {
                unsigned long long other = __shfl_xor(best, o);
                best = other < best ? other : best;
            }
            if (lrow == 0) atomicMin(&minb[m_g], best);
        }
    }
}

// ---------------- Kernel O: coalesced gather via LDS transpose + NCHW write + loss ----------------
// grid: 16 b x 8 ctile x 16 hwtile = 2048 blocks. All global traffic coalesced;
// emb gather reads 256 B contiguous rows (L2/L3-resident codebook).
__global__ __launch_bounds__(256) void ko2(const float* __restrict__ z,
                                           const float* __restrict__ emb,
                                           const unsigned long long* __restrict__ minb,
                                           float* __restrict__ out, float* __restrict__ loss) {
    __shared__ int idx[64];
    __shared__ float qt[64][65];     // [token][c], pad 65 -> conflict-free both phases
    int blk = blockIdx.x;
    int b = blk >> 7, ct = (blk >> 4) & 7, hwt = blk & 15;
    int c0 = ct * 64, hw0 = hwt * 64;
    int tid = threadIdx.x;
    if (tid < 64) idx[tid] = (int)(unsigned int)(minb[b * HW + hw0 + tid] & 0xFFFFFFFFull);
    __syncthreads();
#pragma unroll
    for (int i = 0; i < 16; ++i) {
        int e = tid + 256 * i;               // tr(64) x c(64)
        int tr = e >> 6, c = e & 63;
        qt[tr][c] = emb[(size_t)idx[tr] * D + c0 + c];   // coalesced along c
    }
    __syncthreads();
    float s = 0.f;
    const float* zp = z + ((size_t)b * D + c0) * HW + hw0;
    float*       op = out + ((size_t)b * D + c0) * HW + hw0;
#pragma unroll
    for (int i = 0; i < 16; ++i) {
        int e = tid + 256 * i;               // r(64 channels) x hw(64)
        int r = e >> 6, hw = e & 63;
        float q  = qt[hw][r];                // LDS transpose, conflict-free
        float zv = zp[(size_t)r * HW + hw];  // coalesced
        op[(size_t)r * HW + hw] = q;         // coalesced
        float d = q - zv; s += d * d;
    }
#pragma unroll
    for (int o = 32; o; o >>= 1) s += __shfl_down(s, o);
    __shared__ float ls[4];
    if ((tid & 63) == 0) ls[tid >> 6] = s;
    __syncthreads();
    if (tid == 0) atomicAdd(loss, ls[0] + ls[1] + ls[2] + ls[3]);
}

// ---------------- Kernel F: finalize loss ----------------
__global__ void kf(const float* __restrict__ loss, float* __restrict__ out_loss) {
    *out_loss = 1.25f * (*loss) / 8388608.0f;   // q_latent + 0.25*e_latent
}

extern "C" void kernel_launch(void* const* d_in, const int* in_sizes, int n_in,
                              void* d_out, int out_size, void* d_ws, size_t ws_size,
                              hipStream_t stream) {
    const float* z   = (const float*)d_in[0];   // [16,512,32,32]
    const float* emb = (const float*)d_in[1];   // [2048,512]
    char* ws = (char*)d_ws;
    __hip_bfloat16* zb  = (__hip_bfloat16*)(ws + WS_ZB);
    __hip_bfloat16* eb  = (__hip_bfloat16*)(ws + WS_EB);
    float*          esq = (float*)(ws + WS_ESQ);
    unsigned long long* minb = (unsigned long long*)(ws + WS_MINB);
    float*          loss = (float*)(ws + WS_LOSS);
    float* out = (float*)d_out;

    hipMemsetAsync(minb, 0xFF, N_TOK * 8, stream);  // u64 max
    hipMemsetAsync(loss, 0, 4, stream);
    kz<<<2048, 256, 0, stream>>>(z, zb);
    ke<<<K,    256, 0, stream>>>(emb, eb, esq);
    kg<<<2048, 256, 0, stream>>>(zb, eb, esq, minb);
    ko2<<<2048, 256, 0, stream>>>(z, emb, minb, out, loss);
    kf<<<1, 1, 0, stream>>>(loss, out + NUMEL);
}